// Round 12
// baseline (1121.691 us; speedup 1.0000x reference)
//
#include <hip/hip_runtime.h>
#include <math.h>

// ---------------------------------------------------------------------------
// HyperbolicTemporalEncoder — MFMA fp16-split, packed-atomic edges,
// fused gates+GRU+expmap0+aux (k_gru), fused h_now+u GEMM (k_mmu).
// R12 changes vs R11:
//  1) Concat activation layout: each 128-dim split row stored as one
//     [256-half] row = [hi(128) | lo(128)]. k_agg gathers a full row with ONE
//     f16x4 load/lane (was two): lanes 0-31 sum hi dims, 32-63 lo dims,
//     combined via one shfl at the end. Halves gather issue count.
//  2) k_mmu: u = h_now @ Ct^T fused into the h_now GEMM. The block's acc
//     already holds h_now[128rows][128cols]; per 64-col slab it parks
//     fsplit(h_now) into sA (free after the main K-loop), stages Ct into sW,
//     and accumulates u with the same 3-MFMA split. Kills the u-GEMM's A
//     re-read (102 MB) + one launch. Bit-identical u (same fsplit, order).
// ---------------------------------------------------------------------------

typedef _Float16 f16x8 __attribute__((ext_vector_type(8)));
typedef _Float16 f16x4 __attribute__((ext_vector_type(4)));
typedef _Float16 f16x2 __attribute__((ext_vector_type(2)));
typedef float f32x4 __attribute__((ext_vector_type(4)));

__device__ __forceinline__ float wsum(float v) {
#pragma unroll
  for (int off = 1; off < 64; off <<= 1) v += __shfl_xor(v, off, 64);
  return v;
}

__device__ __forceinline__ void fsplit(float x, _Float16& h, _Float16& l) {
  h = (_Float16)x;
  l = (_Float16)(x - (float)h);
}

// scale s such that logmap0(y) = y * s, for a row with squared norm nrm2
__device__ __forceinline__ float logmap_scale(float nrm2) {
  float n0 = fmaxf(sqrtf(nrm2), 1e-12f);
  float sp = fminf((1.0f - 1e-5f) / n0, 1.0f);
  float np = fmaxf(n0 * sp, 1e-12f);
  float a  = fminf(np, 1.0f - 1e-6f);
  float at = 0.5f * (log1pf(a) - log1pf(-a));
  return sp * at / np;
}

// -------------------- edge atomics (packed u64) --------------------
__global__ void k_edge(const int* __restrict__ ei, const float* __restrict__ t,
                       unsigned long long* __restrict__ packed, int E) {
  int e = blockIdx.x * 256 + threadIdx.x;
  if (e >= E) return;
  int s = ei[e], d = ei[E + e];
  unsigned long long tf =
      (unsigned long long)__float2uint_rn(t[e] * 16777216.0f);  // t in [0,1)
  unsigned long long encs = tf | (1ULL << 40);
  atomicAdd(&packed[s], encs);
  atomicAdd(&packed[d], encs | (1ULL << 52));
}

// -------------------- exclusive scan (3 kernels) --------------------
__global__ void k_scan1(const unsigned long long* __restrict__ packed,
                        int* __restrict__ rowptr, int* __restrict__ bsum, int N) {
  __shared__ int s[256];
  int t = threadIdx.x;
  int base = blockIdx.x * 1024 + t * 4;
  int v[4]; int loc = 0;
#pragma unroll
  for (int j = 0; j < 4; ++j) {
    int i = base + j;
    v[j] = (i < N) ? (int)(packed[i] >> 52) : 0;   // in-degree field
    loc += v[j];
  }
  s[t] = loc; __syncthreads();
  for (int off = 1; off < 256; off <<= 1) {
    int x = (t >= off) ? s[t - off] : 0; __syncthreads();
    s[t] += x; __syncthreads();
  }
  int run = s[t] - loc;
#pragma unroll
  for (int j = 0; j < 4; ++j) { int i = base + j; if (i < N) rowptr[i] = run; run += v[j]; }
  if (t == 255) bsum[blockIdx.x] = s[255];
}

__global__ void k_scan2(const int* __restrict__ bsum, int* __restrict__ boff, int nb) {
  __shared__ int s[128];
  int t = threadIdx.x;
  int v = (t < nb) ? bsum[t] : 0;
  s[t] = v; __syncthreads();
  for (int off = 1; off < 128; off <<= 1) {
    int x = (t >= off) ? s[t - off] : 0; __syncthreads();
    s[t] += x; __syncthreads();
  }
  boff[t] = s[t] - v;
}

__global__ void k_scan3(int* __restrict__ rowptr, const int* __restrict__ boff, int N, int E) {
  int i = blockIdx.x * 256 + threadIdx.x;
  if (i < N) rowptr[i] += boff[i >> 10];
  if (i == 0) rowptr[N] = E;
}

__global__ void k_scatter(const int* __restrict__ ei, const int* __restrict__ rowptr,
                          int* __restrict__ cursor, int* __restrict__ eidx, int E) {
  int e = blockIdx.x * 256 + threadIdx.x;
  if (e >= E) return;
  int s = ei[e], d = ei[E + e];
  int p = rowptr[d] + atomicAdd(&cursor[d], 1);
  eidx[p] = s;
}

// -------------------- x + cos(time*w + b) -> concat split ---------------------
__global__ void k_time(const float* __restrict__ x,
                       const unsigned long long* __restrict__ packed,
                       const float* __restrict__ wt,
                       const float* __restrict__ bt,
                       _Float16* __restrict__ out, int N) {
  int id = blockIdx.x * 256 + threadIdx.x;   // one float4 per thread
  if (id >= N * 32) return;
  int n = id >> 5, q = id & 31;
  unsigned long long p = packed[n];
  float tsum = (float)(p & 0xFFFFFFFFFFULL) * 5.9604644775390625e-8f;  // /2^24
  int c = (int)((p >> 40) & 0xFFF);
  float tm = tsum / fmaxf((float)c, 1.0f);
  float4 xv = ((const float4*)x)[id];
  float4 wv = ((const float4*)wt)[q];
  float4 bv = ((const float4*)bt)[q];
  float o[4];
  o[0] = xv.x + cosf(tm * wv.x + bv.x);
  o[1] = xv.y + cosf(tm * wv.y + bv.y);
  o[2] = xv.z + cosf(tm * wv.z + bv.z);
  o[3] = xv.w + cosf(tm * wv.w + bv.w);
  f16x4 vh, vl;
#pragma unroll
  for (int j = 0; j < 4; ++j) { _Float16 h, l; fsplit(o[j], h, l); vh[j] = h; vl[j] = l; }
  *(f16x4*)&out[(size_t)n * 256 + q * 4] = vh;
  *(f16x4*)&out[(size_t)n * 256 + 128 + q * 4] = vl;
}

// -------------------- CSR mean aggregation (concat, 1 load/lane, 4x unroll) --
__global__ void k_agg(const _Float16* __restrict__ X, const int* __restrict__ rowptr,
                      const int* __restrict__ eidx, _Float16* __restrict__ out, int N) {
  int wid = threadIdx.x >> 6, lane = threadIdx.x & 63;
  int n = blockIdx.x * 4 + wid;
  if (n >= N) return;
  int s0 = rowptr[n], s1 = rowptr[n + 1];
  size_t lo4 = (size_t)lane * 4;                   // lane's 4 halfs of the 256-row
  float a0[4] = {0, 0, 0, 0}, a1[4] = {0, 0, 0, 0};
  float a2[4] = {0, 0, 0, 0}, a3[4] = {0, 0, 0, 0};
  int e = s0;
  for (; e + 4 <= s1; e += 4) {
    int i0 = eidx[e], i1 = eidx[e + 1], i2 = eidx[e + 2], i3 = eidx[e + 3];
    f16x4 v0 = *(const f16x4*)&X[(size_t)i0 * 256 + lo4];
    f16x4 v1 = *(const f16x4*)&X[(size_t)i1 * 256 + lo4];
    f16x4 v2 = *(const f16x4*)&X[(size_t)i2 * 256 + lo4];
    f16x4 v3 = *(const f16x4*)&X[(size_t)i3 * 256 + lo4];
#pragma unroll
    for (int j = 0; j < 4; ++j) {
      a0[j] += (float)v0[j]; a1[j] += (float)v1[j];
      a2[j] += (float)v2[j]; a3[j] += (float)v3[j];
    }
  }
  float a[4];
#pragma unroll
  for (int j = 0; j < 4; ++j) a[j] = (a0[j] + a1[j]) + (a2[j] + a3[j]);
  for (; e < s1; ++e) {
    int s = eidx[e];
    f16x4 v = *(const f16x4*)&X[(size_t)s * 256 + lo4];
#pragma unroll
    for (int j = 0; j < 4; ++j) a[j] += (float)v[j];
  }
  // lanes 0-31 hold hi-dim sums, 32-63 lo-dim sums for the same dims
  float lov[4];
#pragma unroll
  for (int j = 0; j < 4; ++j) lov[j] = __shfl(a[j], lane + 32, 64);
  if (lane < 32) {
    float sc = 1.0f / fmaxf((float)(s1 - s0), 1.0f);
    f16x4 vh, vl;
#pragma unroll
    for (int j = 0; j < 4; ++j) {
      float v = (a[j] + lov[j]) * sc;
      _Float16 h, l; fsplit(v, h, l);
      vh[j] = h; vl[j] = l;
    }
    *(f16x4*)&out[(size_t)n * 256 + lane * 4] = vh;
    *(f16x4*)&out[(size_t)n * 256 + 128 + lane * 4] = vl;
  }
}

// -------------------- weight prep (split fp16, [C][K] layouts) ---------------
__global__ void k_prep(const float* __restrict__ W0l, const float* __restrict__ W0r,
                       const float* __restrict__ W1l, const float* __restrict__ W1r,
                       const float* __restrict__ Wv,  const float* __restrict__ Wih,
                       const float* __restrict__ Whh, const float* __restrict__ bih,
                       const float* __restrict__ bhh,
                       _Float16* __restrict__ W0H, _Float16* __restrict__ W0L,
                       _Float16* __restrict__ W1H, _Float16* __restrict__ W1L,
                       _Float16* __restrict__ WvH, _Float16* __restrict__ WvL,
                       _Float16* __restrict__ WzH, _Float16* __restrict__ WzL,
                       float* __restrict__ bz) {
  int id = blockIdx.x * 256 + threadIdx.x;
  if (id < 32768) {
    int c = id >> 8, k = id & 255;
    float v0 = (k < 128) ? W0l[c * 128 + k] : W0r[c * 128 + (k - 128)];
    float v1 = (k < 128) ? W1l[c * 128 + k] : W1r[c * 128 + (k - 128)];
    fsplit(v0, W0H[id], W0L[id]);
    fsplit(v1, W1H[id], W1L[id]);
  }
  if (id < 16384) {
    fsplit(Wv[id], WvH[id], WvL[id]);   // Wv already [C][K]
  }
  if (id < 131072) {
    int c = id >> 8, k = id & 255;
    float v;
    if (c < 256)      v = (k < 128) ? Wih[c * 128 + k] : Whh[c * 128 + (k - 128)];
    else if (c < 384) v = (k < 128) ? Wih[c * 128 + k] : 0.f;
    else              v = (k < 128) ? 0.f : Whh[(c - 128) * 128 + (k - 128)];
    fsplit(v, WzH[id], WzL[id]);
  }
  if (id < 512) {
    float v;
    if (id < 256)      v = bih[id] + bhh[id];
    else if (id < 384) v = bih[id];
    else               v = bhh[id - 128];
    bz[id] = v;
  }
}

// Ct'[c][k] = sum_j Wk[j][c] * Wq[j][k]  (u = h_now @ Ct'^T => score = ht.u)
__global__ void k_ct(const float* __restrict__ Wk, const float* __restrict__ Wq,
                     _Float16* __restrict__ CtH, _Float16* __restrict__ CtL) {
  int id = blockIdx.x * 256 + threadIdx.x;
  if (id >= 16384) return;
  int c = id >> 7, k = id & 127;
  float s = 0.f;
  for (int j = 0; j < 128; ++j) s += Wk[j * 128 + c] * Wq[j * 128 + k];
  fsplit(s, CtH[id], CtL[id]);
}

// per-row logmap0 scale of prev
__global__ void k_lognorm(const float* __restrict__ Y, float* __restrict__ scale, int N) {
  int wid = threadIdx.x >> 6, lane = threadIdx.x & 63;
  int n = blockIdx.x * 4 + wid;
  if (n >= N) return;
  float2 y = ((const float2*)Y)[(size_t)n * 64 + lane];
  float nrm2 = wsum(y.x * y.x + y.y * y.y);
  if (lane == 0) scale[n] = logmap_scale(nrm2);
}

// -------------------- MFMA fp16-split GEMM (concat activations) --------------
// out[n][c] = sum_k A[n][k]*W[c][k] (+bias[c]) (+addb[n][c]*(scalev?scalev[n]:1)) (relu?)
// A1/A2: concat [N][256-half] rows (hi|lo); A1 covers k<128, A2 k>=128.
__global__ __launch_bounds__(256)
void k_mm(const _Float16* __restrict__ A1, const _Float16* __restrict__ A2,
          const _Float16* __restrict__ WH,  const _Float16* __restrict__ WL,
          const float* __restrict__ bias,   const float* __restrict__ addb,
          const float* __restrict__ scalev,
          float* __restrict__ outF, _Float16* __restrict__ outS,
          int Nrows, int Ktot, int Ctot, int relu) {
  __shared__ _Float16 sA[2][128][64];   // [hi/lo][row][k]  32 KiB
  __shared__ _Float16 sW[2][128][64];   //                   32 KiB
  const int tid = threadIdx.x;
  const int lane = tid & 63;
  const int wv = tid >> 6;
  const int wr = wv >> 1, wc = wv & 1;         // wave grid 2x2
  const int laneR = lane & 15, laneG = lane >> 4;
  const int n0 = blockIdx.x * 128;
  const int c0 = blockIdx.y * 128;

  f32x4 acc[4][4];
#pragma unroll
  for (int mi = 0; mi < 4; ++mi)
#pragma unroll
    for (int ni = 0; ni < 4; ++ni)
#pragma unroll
      for (int j = 0; j < 4; ++j) acc[mi][ni][j] = 0.f;

  const int nslab = Ktot >> 6;
  for (int s = 0; s < nslab; ++s) {
    int kglob = s << 6;
    const _Float16* Ax = (kglob < 128) ? A1 : A2;
    int kc = kglob & 127;
    __syncthreads();   // previous compute done before overwriting LDS
#pragma unroll
    for (int it = 0; it < 4; ++it) {
      int idx = tid + (it << 8);
      int r = idx >> 3, chunk = idx & 7;   // 16B chunks of 8 halfs
      int cs = (chunk ^ (r & 7)) << 3;     // swizzled half offset
      int kq = chunk << 3;
      int n = n0 + r;
      f16x8 vh, vl;
      if (n < Nrows) {
        vh = *(const f16x8*)&Ax[(size_t)n * 256 + kc + kq];
        vl = *(const f16x8*)&Ax[(size_t)n * 256 + 128 + kc + kq];
      } else {
#pragma unroll
        for (int j = 0; j < 8; ++j) { vh[j] = (_Float16)0; vl[j] = (_Float16)0; }
      }
      *(f16x8*)&sA[0][r][cs] = vh;
      *(f16x8*)&sA[1][r][cs] = vl;
      int c = c0 + r;
      f16x8 wh = *(const f16x8*)&WH[(size_t)c * Ktot + kglob + kq];
      f16x8 wl = *(const f16x8*)&WL[(size_t)c * Ktot + kglob + kq];
      *(f16x8*)&sW[0][r][cs] = wh;
      *(f16x8*)&sW[1][r][cs] = wl;
    }
    __syncthreads();
#pragma unroll
    for (int kk = 0; kk < 2; ++kk) {
      f16x8 ah[4], al[4], bh[4], bl[4];
      int kch = (kk << 2) + laneG;         // 16B chunk index 0..7
#pragma unroll
      for (int m = 0; m < 4; ++m) {
        int row = wr * 64 + m * 16 + laneR;
        int ko = (kch ^ (row & 7)) << 3;
        ah[m] = *(const f16x8*)&sA[0][row][ko];
        al[m] = *(const f16x8*)&sA[1][row][ko];
      }
#pragma unroll
      for (int n = 0; n < 4; ++n) {
        int row = wc * 64 + n * 16 + laneR;
        int ko = (kch ^ (row & 7)) << 3;
        bh[n] = *(const f16x8*)&sW[0][row][ko];
        bl[n] = *(const f16x8*)&sW[1][row][ko];
      }
#pragma unroll
      for (int m = 0; m < 4; ++m)
#pragma unroll
        for (int n = 0; n < 4; ++n) {
          acc[m][n] = __builtin_amdgcn_mfma_f32_16x16x32_f16(ah[m], bh[n], acc[m][n], 0, 0, 0);
          acc[m][n] = __builtin_amdgcn_mfma_f32_16x16x32_f16(al[m], bh[n], acc[m][n], 0, 0, 0);
          acc[m][n] = __builtin_amdgcn_mfma_f32_16x16x32_f16(ah[m], bl[n], acc[m][n], 0, 0, 0);
        }
    }
  }
#pragma unroll
  for (int m = 0; m < 4; ++m) {
#pragma unroll
    for (int n = 0; n < 4; ++n) {
      int rbase = n0 + wr * 64 + m * 16 + laneG * 4;
      int c = c0 + wc * 64 + n * 16 + laneR;
      float bval = bias ? bias[c] : 0.f;
#pragma unroll
      for (int j = 0; j < 4; ++j) {
        int r = rbase + j;
        if (r >= Nrows) continue;
        float v = acc[m][n][j] + bval;
        if (addb) {
          float ab = addb[(size_t)r * Ctot + c];
          v += scalev ? ab * scalev[r] : ab;
        }
        if (relu) v = fmaxf(v, 0.f);
        if (outF) outF[(size_t)r * Ctot + c] = v;
        if (outS) {
          _Float16 h, l; fsplit(v, h, l);
          outS[(size_t)r * 256 + c] = h;
          outS[(size_t)r * 256 + 128 + c] = l;
        }
      }
    }
  }
}

// -------------------- fused h_now GEMM + u GEMM (k_mmu) ----------------------
// Phase 1: h_now = [A1|A2] @ W1^T + b1 (standard, K=256).
// Phase 2: u = h_now @ Ct^T. Per 64-col slab: waves owning those cols park
// fsplit(h_now) into sA (swizzled), Ct slab staged into sW, 3-MFMA accumulate.
// Outputs: h_now concat -> outS, u fp32 -> outU. Bit-identical to the split
// h_now k_mm + u k_mm pair.
__global__ __launch_bounds__(256)
void k_mmu(const _Float16* __restrict__ A1, const _Float16* __restrict__ A2,
           const _Float16* __restrict__ WH, const _Float16* __restrict__ WL,
           const _Float16* __restrict__ CtH, const _Float16* __restrict__ CtL,
           const float* __restrict__ bias,
           _Float16* __restrict__ outS, float* __restrict__ outU, int Nrows) {
  __shared__ _Float16 sA[2][128][64];
  __shared__ _Float16 sW[2][128][64];
  const int tid = threadIdx.x;
  const int lane = tid & 63;
  const int wv = tid >> 6;
  const int wr = wv >> 1, wc = wv & 1;
  const int laneR = lane & 15, laneG = lane >> 4;
  const int n0 = blockIdx.x * 128;

  f32x4 acc[4][4];
#pragma unroll
  for (int mi = 0; mi < 4; ++mi)
#pragma unroll
    for (int ni = 0; ni < 4; ++ni)
#pragma unroll
      for (int j = 0; j < 4; ++j) acc[mi][ni][j] = 0.f;

  // ---- phase 1: h_now (K = 256)
  for (int s = 0; s < 4; ++s) {
    int kglob = s << 6;
    const _Float16* Ax = (kglob < 128) ? A1 : A2;
    int kc = kglob & 127;
    __syncthreads();
#pragma unroll
    for (int it = 0; it < 4; ++it) {
      int idx = tid + (it << 8);
      int r = idx >> 3, chunk = idx & 7;
      int cs = (chunk ^ (r & 7)) << 3;
      int kq = chunk << 3;
      int n = n0 + r;
      f16x8 vh, vl;
      if (n < Nrows) {
        vh = *(const f16x8*)&Ax[(size_t)n * 256 + kc + kq];
        vl = *(const f16x8*)&Ax[(size_t)n * 256 + 128 + kc + kq];
      } else {
#pragma unroll
        for (int j = 0; j < 8; ++j) { vh[j] = (_Float16)0; vl[j] = (_Float16)0; }
      }
      *(f16x8*)&sA[0][r][cs] = vh;
      *(f16x8*)&sA[1][r][cs] = vl;
      f16x8 wh = *(const f16x8*)&WH[(size_t)r * 256 + kglob + kq];
      f16x8 wl = *(const f16x8*)&WL[(size_t)r * 256 + kglob + kq];
      *(f16x8*)&sW[0][r][cs] = wh;
      *(f16x8*)&sW[1][r][cs] = wl;
    }
    __syncthreads();
#pragma unroll
    for (int kk = 0; kk < 2; ++kk) {
      f16x8 ah[4], al[4], bh[4], bl[4];
      int kch = (kk << 2) + laneG;
#pragma unroll
      for (int m = 0; m < 4; ++m) {
        int row = wr * 64 + m * 16 + laneR;
        int ko = (kch ^ (row & 7)) << 3;
        ah[m] = *(const f16x8*)&sA[0][row][ko];
        al[m] = *(const f16x8*)&sA[1][row][ko];
      }
#pragma unroll
      for (int n = 0; n < 4; ++n) {
        int row = wc * 64 + n * 16 + laneR;
        int ko = (kch ^ (row & 7)) << 3;
        bh[n] = *(const f16x8*)&sW[0][row][ko];
        bl[n] = *(const f16x8*)&sW[1][row][ko];
      }
#pragma unroll
      for (int m = 0; m < 4; ++m)
#pragma unroll
        for (int n = 0; n < 4; ++n) {
          acc[m][n] = __builtin_amdgcn_mfma_f32_16x16x32_f16(ah[m], bh[n], acc[m][n], 0, 0, 0);
          acc[m][n] = __builtin_amdgcn_mfma_f32_16x16x32_f16(al[m], bh[n], acc[m][n], 0, 0, 0);
          acc[m][n] = __builtin_amdgcn_mfma_f32_16x16x32_f16(ah[m], bl[n], acc[m][n], 0, 0, 0);
        }
    }
  }

  // ---- phase 2: u = h_now @ Ct^T (K = 128, two 64-wide slabs)
  f32x4 accU[4][4];
#pragma unroll
  for (int mi = 0; mi < 4; ++mi)
#pragma unroll
    for (int ni = 0; ni < 4; ++ni)
#pragma unroll
      for (int j = 0; j < 4; ++j) accU[mi][ni][j] = 0.f;

  for (int us = 0; us < 2; ++us) {
    __syncthreads();                         // prior sA/sW reads done
    if (wc == us) {                          // park my h_now cols into sA
#pragma unroll
      for (int m = 0; m < 4; ++m)
#pragma unroll
        for (int n = 0; n < 4; ++n) {
          int kp = n * 16 + laneR;           // local k within slab (= col - 64*us)
          float bval = bias[us * 64 + n * 16 + laneR];
#pragma unroll
          for (int j = 0; j < 4; ++j) {
            int row = wr * 64 + m * 16 + laneG * 4 + j;
            float v = acc[m][n][j] + bval;
            _Float16 h, l; fsplit(v, h, l);
            int cs = ((kp >> 3) ^ (row & 7)) * 8 + (kp & 7);
            sA[0][row][cs] = h;
            sA[1][row][cs] = l;
          }
        }
    }
#pragma unroll
    for (int it = 0; it < 4; ++it) {         // stage Ct slab into sW
      int idx = tid + (it << 8);
      int r = idx >> 3, chunk = idx & 7;
      int cs = (chunk ^ (r & 7)) << 3;
      int kq = chunk << 3;
      *(f16x8*)&sW[0][r][cs] = *(const f16x8*)&CtH[(size_t)r * 128 + us * 64 + kq];
      *(f16x8*)&sW[1][r][cs] = *(const f16x8*)&CtL[(size_t)r * 128 + us * 64 + kq];
    }
    __syncthreads();
#pragma unroll
    for (int kk = 0; kk < 2; ++kk) {
      f16x8 ah[4], al[4], bh[4], bl[4];
      int kch = (kk << 2) + laneG;
#pragma unroll
      for (int m = 0; m < 4; ++m) {
        int row = wr * 64 + m * 16 + laneR;
        int ko = (kch ^ (row & 7)) << 3;
        ah[m] = *(const f16x8*)&sA[0][row][ko];
        al[m] = *(const f16x8*)&sA[1][row][ko];
      }
#pragma unroll
      for (int n = 0; n < 4; ++n) {
        int row = wc * 64 + n * 16 + laneR;
        int ko = (kch ^ (row & 7)) << 3;
        bh[n] = *(const f16x8*)&sW[0][row][ko];
        bl[n] = *(const f16x8*)&sW[1][row][ko];
      }
#pragma unroll
      for (int m = 0; m < 4; ++m)
#pragma unroll
        for (int n = 0; n < 4; ++n) {
          accU[m][n] = __builtin_amdgcn_mfma_f32_16x16x32_f16(ah[m], bh[n], accU[m][n], 0, 0, 0);
          accU[m][n] = __builtin_amdgcn_mfma_f32_16x16x32_f16(al[m], bh[n], accU[m][n], 0, 0, 0);
          accU[m][n] = __builtin_amdgcn_mfma_f32_16x16x32_f16(ah[m], bl[n], accU[m][n], 0, 0, 0);
        }
    }
  }

  // ---- epilogue: h_now -> outS (concat), u -> outU (fp32)
#pragma unroll
  for (int m = 0; m < 4; ++m) {
#pragma unroll
    for (int n = 0; n < 4; ++n) {
      int rbase = n0 + wr * 64 + m * 16 + laneG * 4;
      int c = wc * 64 + n * 16 + laneR;
      float bval = bias[c];
#pragma unroll
      for (int j = 0; j < 4; ++j) {
        int r = rbase + j;
        if (r >= Nrows) continue;
        float v = acc[m][n][j] + bval;
        _Float16 h, l; fsplit(v, h, l);
        outS[(size_t)r * 256 + c] = h;
        outS[(size_t)r * 256 + 128 + c] = l;
        outU[(size_t)r * 128 + c] = accU[m][n][j];
      }
    }
  }
}

// -------------------- history attention -> concat split ctxt -----------------
__global__ void k_attn(const float* __restrict__ U, const float* __restrict__ hist,
                       _Float16* __restrict__ out, int N) {
  int wid = threadIdx.x >> 6, lane = threadIdx.x & 63;
  int n = blockIdx.x * 4 + wid;
  if (n >= N) return;
  float2 u = ((const float2*)U)[(size_t)n * 64 + lane];
  float htx[3], hty[3], sc[3];
  bool val[3];
#pragma unroll
  for (int w = 0; w < 3; ++w) {
    float2 h = ((const float2*)hist)[((size_t)n * 3 + w) * 64 + lane];
    float nrm2 = wsum(h.x * h.x + h.y * h.y);
    val[w] = nrm2 > 0.f;
    float s = logmap_scale(nrm2);
    htx[w] = h.x * s; hty[w] = h.y * s;
    float d = wsum(htx[w] * u.x + hty[w] * u.y);
    sc[w] = d * 0.0883883476483184f;   // 1/sqrt(128), TEMP=1
  }
  float cx = 0.f, cy = 0.f;
  if (val[0] || val[1] || val[2]) {
    float m = -INFINITY;
#pragma unroll
    for (int w = 0; w < 3; ++w) if (val[w]) m = fmaxf(m, sc[w]);
    float a[3]; float ssum = 0.f;
#pragma unroll
    for (int w = 0; w < 3; ++w) { a[w] = val[w] ? expf(sc[w] - m) : 0.f; ssum += a[w]; }
    float inv = 1.f / ssum;
#pragma unroll
    for (int w = 0; w < 3; ++w) { cx += htx[w] * (a[w] * inv); cy += hty[w] * (a[w] * inv); }
  }
  _Float16 hx, lx, hy, ly;
  fsplit(cx, hx, lx); fsplit(cy, hy, ly);
  f16x2 vh = {hx, hy}, vl = {lx, ly};
  *(f16x2*)&out[(size_t)n * 256 + lane * 2] = vh;
  *(f16x2*)&out[(size_t)n * 256 + 128 + lane * 2] = vl;
}

// -------------------- fused gates GEMM + GRU + expmap0 + aux -----------------
// R5 structure (measured best) + bit-exact zero-quadrant-slab skip.
__global__ __launch_bounds__(256, 2)
void k_gru(const _Float16* __restrict__ P0c, const _Float16* __restrict__ P2c,
           const _Float16* __restrict__ WzH, const _Float16* __restrict__ WzL,
           const float* __restrict__ bz, const float* __restrict__ prev,
           float* __restrict__ out, float* __restrict__ pd,
           float* __restrict__ pv, int N) {
  __shared__ _Float16 sA[2][64][64];    // 16 KiB
  __shared__ _Float16 sW[2][128][64];   // 32 KiB
  __shared__ float rn1[64][2];
  __shared__ float rn3[64][2][3];
  __shared__ float distrow[64], validrow[64];
  const int tid = threadIdx.x;
  const int lane = tid & 63;
  const int wv = tid >> 6;
  const int wr = wv >> 1, wc = wv & 1;          // wave grid 2(row) x 2(col)
  const int laneR = lane & 15, laneG = lane >> 4;
  const int n0 = blockIdx.x * 64;

  f32x4 acc[4][2][4];                            // [quadrant][m][n]
#pragma unroll
  for (int q = 0; q < 4; ++q)
#pragma unroll
    for (int m = 0; m < 2; ++m)
#pragma unroll
      for (int n = 0; n < 4; ++n)
#pragma unroll
        for (int j = 0; j < 4; ++j) acc[q][m][n][j] = 0.f;

#define STAGE_W(Q)                                                          \
  {                                                                         \
    _Pragma("unroll")                                                       \
    for (int it = 0; it < 4; ++it) {                                        \
      int idx = tid + (it << 8);                                            \
      int r = idx >> 3, chunk = idx & 7;                                    \
      int cs = (chunk ^ (r & 7)) << 3;                                      \
      int kq = chunk << 3;                                                  \
      size_t wrow = (size_t)((Q)*128 + r);                                  \
      *(f16x8*)&sW[0][r][cs] = *(const f16x8*)&WzH[wrow * 256 + kglob + kq];\
      *(f16x8*)&sW[1][r][cs] = *(const f16x8*)&WzL[wrow * 256 + kglob + kq];\
    }                                                                       \
  }

#define COMPUTE_Q(Q)                                                        \
  {                                                                         \
    _Pragma("unroll")                                                       \
    for (int kk = 0; kk < 2; ++kk) {                                        \
      int kch = (kk << 2) + laneG;                                          \
      f16x8 ah[2], al[2], bh[4], bl[4];                                     \
      _Pragma("unroll")                                                     \
      for (int m = 0; m < 2; ++m) {                                         \
        int row = wr * 32 + m * 16 + laneR;                                 \
        int ko = (kch ^ (row & 7)) << 3;                                    \
        ah[m] = *(const f16x8*)&sA[0][row][ko];                             \
        al[m] = *(const f16x8*)&sA[1][row][ko];                             \
      }                                                                     \
      _Pragma("unroll")                                                     \
      for (int n = 0; n < 4; ++n) {                                         \
        int row = wc * 64 + n * 16 + laneR;                                 \
        int ko = (kch ^ (row & 7)) << 3;                                    \
        bh[n] = *(const f16x8*)&sW[0][row][ko];                             \
        bl[n] = *(const f16x8*)&sW[1][row][ko];                             \
      }                                                                     \
      _Pragma("unroll")                                                     \
      for (int m = 0; m < 2; ++m)                                           \
        _Pragma("unroll")                                                   \
        for (int n = 0; n < 4; ++n) {                                       \
          acc[Q][m][n] = __builtin_amdgcn_mfma_f32_16x16x32_f16(ah[m], bh[n], acc[Q][m][n], 0, 0, 0); \
          acc[Q][m][n] = __builtin_amdgcn_mfma_f32_16x16x32_f16(al[m], bh[n], acc[Q][m][n], 0, 0, 0); \
          acc[Q][m][n] = __builtin_amdgcn_mfma_f32_16x16x32_f16(ah[m], bl[n], acc[Q][m][n], 0, 0, 0); \
        }                                                                   \
    }                                                                       \
  }

#pragma unroll
  for (int s = 0; s < 4; ++s) {                  // 4 K-slabs of 64
    int kglob = s << 6;
    const _Float16* Ax = (s < 2) ? P0c : P2c;
    int kc = kglob & 127;
    __syncthreads();                             // prev slab's LDS reads done
#pragma unroll
    for (int it = 0; it < 2; ++it) {             // A: 64 rows x 8 chunks
      int idx = tid + (it << 8);
      int r = idx >> 3, chunk = idx & 7;
      int cs = (chunk ^ (r & 7)) << 3;
      int kq = chunk << 3;
      int n = n0 + r;
      f16x8 vh, vl;
      if (n < N) {
        vh = *(const f16x8*)&Ax[(size_t)n * 256 + kc + kq];
        vl = *(const f16x8*)&Ax[(size_t)n * 256 + 128 + kc + kq];
      } else {
#pragma unroll
        for (int j = 0; j < 8; ++j) { vh[j] = (_Float16)0; vl[j] = (_Float16)0; }
      }
      *(f16x8*)&sA[0][r][cs] = vh;
      *(f16x8*)&sA[1][r][cs] = vl;
    }
    STAGE_W(0);
    __syncthreads();           // A + W0 visible
    COMPUTE_Q(0);
    __syncthreads();           // q0 reads done
    STAGE_W(1);
    __syncthreads();
    COMPUTE_Q(1);
    __syncthreads();           // q1 reads done
    if (s < 2) {
      STAGE_W(2);
      __syncthreads();
      COMPUTE_Q(2);            // i_n: only k<128 contributes
    } else {
      STAGE_W(3);
      __syncthreads();
      COMPUTE_Q(3);            // h_n: only k>=128 contributes
    }
  }
#undef STAGE_W
#undef COMPUTE_Q

  // ---- GRU epilogue. position: row = n0+wr*32+m*16+laneG*4+j, d = wc*64+n*16+laneR
  float bz0[4], bz1[4], bz2[4], bz3[4];
#pragma unroll
  for (int n = 0; n < 4; ++n) {
    int d = wc * 64 + n * 16 + laneR;
    bz0[n] = bz[d]; bz1[n] = bz[128 + d]; bz2[n] = bz[256 + d]; bz3[n] = bz[384 + d];
  }
  float tv[2][4][4];
#pragma unroll
  for (int m = 0; m < 2; ++m)
#pragma unroll
    for (int n = 0; n < 4; ++n)
#pragma unroll
      for (int j = 0; j < 4; ++j) {
        int row = n0 + wr * 32 + m * 16 + laneG * 4 + j;
        int d = wc * 64 + n * 16 + laneR;
        float hid = 0.f;
        if (row < N) {
          size_t o = (size_t)row * 256 + d;
          hid = (float)P2c[o] + (float)P2c[o + 128];
        }
        float gr = acc[0][m][n][j] + bz0[n];
        float gz = acc[1][m][n][j] + bz1[n];
        float gi = acc[2][m][n][j] + bz2[n];
        float gh = acc[3][m][n][j] + bz3[n];
        float rr = 1.f / (1.f + expf(-gr));
        float zz = 1.f / (1.f + expf(-gz));
        float nn = tanhf(gi + rr * gh);
        tv[m][n][j] = (1.f - zz) * nn + zz * hid;
      }
  // row norms of t_tan
#pragma unroll
  for (int m = 0; m < 2; ++m)
#pragma unroll
    for (int j = 0; j < 4; ++j) {
      float p = 0.f;
#pragma unroll
      for (int n = 0; n < 4; ++n) p += tv[m][n][j] * tv[m][n][j];
#pragma unroll
      for (int off = 1; off < 16; off <<= 1) p += __shfl_xor(p, off, 64);
      if (laneR == 0) rn1[wr * 32 + m * 16 + laneG * 4 + j][wc] = p;
    }
  __syncthreads();
  // expmap0 + output store + aux partials
  float hv[2][4][4];
#pragma unroll
  for (int m = 0; m < 2; ++m)
#pragma unroll
    for (int j = 0; j < 4; ++j) {
      int rl = wr * 32 + m * 16 + laneG * 4 + j;
      int row = n0 + rl;
      float nv2 = rn1[rl][0] + rn1[rl][1];
      float nv = fmaxf(sqrtf(nv2), 1e-12f);
      float tn = tanhf(nv);
      float s1 = tn / nv;
      float nw = fmaxf(tn, 1e-12f);
      float sp = fminf((1.f - 1e-5f) / nw, 1.f);
      float scl = s1 * sp;
#pragma unroll
      for (int n = 0; n < 4; ++n) {
        float h = tv[m][n][j] * scl;
        hv[m][n][j] = h;
        int d = wc * 64 + n * 16 + laneR;
        if (row < N) out[(size_t)row * 128 + d] = h;
      }
    }
#pragma unroll
  for (int m = 0; m < 2; ++m)
#pragma unroll
    for (int j = 0; j < 4; ++j) {
      int rl = wr * 32 + m * 16 + laneG * 4 + j;
      int row = n0 + rl;
      float ys = 0.f, ds = 0.f, pa = 0.f;
#pragma unroll
      for (int n = 0; n < 4; ++n) {
        int d = wc * 64 + n * 16 + laneR;
        float p = (row < N) ? prev[(size_t)row * 128 + d] : 0.f;
        float h = hv[m][n][j];
        ys += p * p; ds += (h - p) * (h - p); pa += fabsf(p);
      }
#pragma unroll
      for (int off = 1; off < 16; off <<= 1) {
        ys += __shfl_xor(ys, off, 64);
        ds += __shfl_xor(ds, off, 64);
        pa += __shfl_xor(pa, off, 64);
      }
      if (laneR == 0) { rn3[rl][wc][0] = ys; rn3[rl][wc][1] = ds; rn3[rl][wc][2] = pa; }
    }
  __syncthreads();
  if (wc == 0 && laneR == 0) {
#pragma unroll
    for (int m = 0; m < 2; ++m)
#pragma unroll
      for (int j = 0; j < 4; ++j) {
        int rl = wr * 32 + m * 16 + laneG * 4 + j;
        int row = n0 + rl;
        float nv2 = rn1[rl][0] + rn1[rl][1];
        float nv = fmaxf(sqrtf(nv2), 1e-12f);
        float tn = tanhf(nv);
        float s1 = tn / nv;
        float nw = fmaxf(tn, 1e-12f);
        float sp = fminf((1.f - 1e-5f) / nw, 1.f);
        float scl = s1 * sp;
        float x_sq = scl * scl * nv2;
        float y_sq = rn3[rl][0][0] + rn3[rl][1][0];
        float d_sq = rn3[rl][0][1] + rn3[rl][1][1];
        float pab  = rn3[rl][0][2] + rn3[rl][1][2];
        float denom = fmaxf((1.f - x_sq) * (1.f - y_sq), 1e-8f);
        float zarg = fmaxf(1.f + 2.f * d_sq / denom, 1.f + 1e-6f);
        float dist = acoshf(zarg);
        float valid = (pab > 0.f && row < N) ? 1.f : 0.f;
        distrow[rl] = dist * valid;
        validrow[rl] = valid;
      }
  }
  __syncthreads();
  if (tid < 64) {
    float dv = distrow[tid], vvv = validrow[tid];
    dv = wsum(dv); vvv = wsum(vvv);
    if (tid == 0) { pd[blockIdx.x] = dv; pv[blockIdx.x] = vvv; }
  }
}

__global__ void k_reduce(const float* __restrict__ pd, const float* __restrict__ pv,
                         float* __restrict__ aux_out, int nparts) {
  __shared__ float sd[256], sv[256];
  float a = 0.f, b = 0.f;
  for (int i = threadIdx.x; i < nparts; i += 256) { a += pd[i]; b += pv[i]; }
  sd[threadIdx.x] = a; sv[threadIdx.x] = b; __syncthreads();
  for (int off = 128; off > 0; off >>= 1) {
    if (threadIdx.x < off) { sd[threadIdx.x] += sd[threadIdx.x + off]; sv[threadIdx.x] += sv[threadIdx.x + off]; }
    __syncthreads();
  }
  if (threadIdx.x == 0) {
    float aux = (sv[0] > 0.f) ? 0.01f * sd[0] / fmaxf(sv[0], 1.f) : 0.f;
    aux_out[0] = aux;
  }
}

// ---------------------------------------------------------------------------
extern "C" void kernel_launch(void* const* d_in, const int* in_sizes, int n_in,
                              void* d_out, int out_size, void* d_ws, size_t ws_size,
                              hipStream_t stream) {
  const float* x      = (const float*)d_in[0];
  const int*   ei     = (const int*)  d_in[1];
  const float* t      = (const float*)d_in[2];
  const float* prev   = (const float*)d_in[3];
  const float* hist   = (const float*)d_in[4];
  // d_in[5] = valid_mask (bool) — unused: padded hist slots are exactly zero.
  const float* w_time = (const float*)d_in[6];
  const float* b_time = (const float*)d_in[7];
  const float* W0l    = (const float*)d_in[8];
  const float* b0l    = (const float*)d_in[9];
  const float* W0r    = (const float*)d_in[10];
  const float* W1l    = (const float*)d_in[11];
  const float* b1l    = (const float*)d_in[12];
  const float* W1r    = (const float*)d_in[13];
  const float* Wih    = (const float*)d_in[14];
  const float* Whh    = (const float*)d_in[15];
  const float* bih    = (const float*)d_in[16];
  const float* bhh    = (const float*)d_in[17];
  const float* Wq     = (const float*)d_in[18];
  const float* Wk     = (const float*)d_in[19];
  const float* Wv     = (const float*)d_in[20];

  const int N = in_sizes[0] / 128;
  const int E = in_sizes[1] / 2;
  const int NB4 = (N + 3) / 4;
  const int NB1 = (N + 1023) / 1024;
  const int NBG = (N + 63) / 64;

  char* wbase = (char*)d_ws;
  size_t off = 0;
  auto alloc = [&](size_t bytes) -> void* {
    off = (off + 255) & ~(size_t)255;
    void* p = wbase + off; off += bytes; return p;
  };
  unsigned long long* packed = (unsigned long long*)alloc((size_t)N * 8);
  int*   cursor = (int*)  alloc((size_t)N * 4);
  size_t zero_bytes = off;                 // packed + cursor contiguous from base
  int*   rowptr = (int*)  alloc((size_t)(N + 1) * 4);
  int*   bsum   = (int*)  alloc(512);
  int*   boff   = (int*)  alloc(512);
  int*   eidx   = (int*)  alloc((size_t)E * 4);
  // split weights (fp16 hi/lo)
  _Float16* W0H = (_Float16*)alloc(32768 * 2);
  _Float16* W0L = (_Float16*)alloc(32768 * 2);
  _Float16* W1H = (_Float16*)alloc(32768 * 2);
  _Float16* W1L = (_Float16*)alloc(32768 * 2);
  _Float16* CtH = (_Float16*)alloc(16384 * 2);
  _Float16* CtL = (_Float16*)alloc(16384 * 2);
  _Float16* WvH = (_Float16*)alloc(16384 * 2);
  _Float16* WvL = (_Float16*)alloc(16384 * 2);
  _Float16* WzH = (_Float16*)alloc(131072 * 2);
  _Float16* WzL = (_Float16*)alloc(131072 * 2);
  float* bz     = (float*)alloc(512 * 4);
  float* scale  = (float*)alloc((size_t)N * 4);           // logmap0 row scales
  float* F0     = (float*)alloc((size_t)N * 128 * 4);     // u (fp32)
  // concat split activations ([N][256-half] rows = hi|lo), reused across phases
  _Float16* P0c = (_Float16*)alloc((size_t)N * 256 * 2);  // x' -> h_now
  _Float16* P1c = (_Float16*)alloc((size_t)N * 256 * 2);  // agg0 -> agg1 -> ctx
  _Float16* P2c = (_Float16*)alloc((size_t)N * 256 * 2);  // h -> HID
  float* pd = (float*)alloc((size_t)NBG * 4);
  float* pv = (float*)alloc((size_t)NBG * 4);
  (void)ws_size; (void)n_in; (void)out_size;

  float* out_h   = (float*)d_out;
  float* out_aux = out_h + (size_t)N * 128;

  hipMemsetAsync(d_ws, 0, zero_bytes, stream);   // packed, cursor

  // weight prep
  k_prep<<<512, 256, 0, stream>>>(W0l, W0r, W1l, W1r, Wv, Wih, Whh, bih, bhh,
                                  W0H, W0L, W1H, W1L, WvH, WvL, WzH, WzL, bz);
  k_ct<<<64, 256, 0, stream>>>(Wk, Wq, CtH, CtL);
  k_lognorm<<<NB4, 256, 0, stream>>>(prev, scale, N);

  // graph preprocessing
  int ebl = (E + 255) / 256;
  k_edge<<<ebl, 256, 0, stream>>>(ei, t, packed, E);
  k_scan1<<<NB1, 256, 0, stream>>>(packed, rowptr, bsum, N);
  k_scan2<<<1, 128, 0, stream>>>(bsum, boff, NB1);
  k_scan3<<<(N + 255) / 256, 256, 0, stream>>>(rowptr, boff, N, E);
  k_scatter<<<ebl, 256, 0, stream>>>(ei, rowptr, cursor, eidx, E);

  // node pipeline
  k_time<<<(N * 32 + 255) / 256, 256, 0, stream>>>(x, packed, w_time, b_time,
                                                   P0c, N);
  k_agg<<<NB4, 256, 0, stream>>>(P0c, rowptr, eidx, P1c, N);                // agg0
  dim3 gb((N + 127) / 128, 1);
  // h = relu([agg0|x'] @ Wt0^T + b0)  -> P2 concat
  k_mm<<<gb, 256, 0, stream>>>(P1c, P0c, W0H, W0L, b0l, nullptr, nullptr,
                               nullptr, P2c, N, 256, 128, 1);
  k_agg<<<NB4, 256, 0, stream>>>(P2c, rowptr, eidx, P1c, N);                // agg1
  // h_now = [agg1|h] @ Wt1^T + b1 -> P0 concat; u = h_now @ Ct^T -> F0
  k_mmu<<<gb, 256, 0, stream>>>(P1c, P2c, W1H, W1L, CtH, CtL, b1l, P0c, F0, N);
  k_attn<<<NB4, 256, 0, stream>>>(F0, hist, P1c, N);                        // ctxt
  // HID = ctx @ Wv^T + prev*scale -> P2 concat
  k_mm<<<gb, 256, 0, stream>>>(P1c, nullptr, WvH, WvL, nullptr, prev, scale,
                               nullptr, P2c, N, 128, 128, 0);
  // fused gates + GRU + expmap0 + aux
  k_gru<<<NBG, 256, 0, stream>>>(P0c, P2c, WzH, WzL, bz, prev,
                                 out_h, pd, pv, N);
  k_reduce<<<1, 256, 0, stream>>>(pd, pv, out_aux, NBG);
}